// Round 7
// baseline (188.942 us; speedup 1.0000x reference)
//
#include <hip/hip_runtime.h>

#define BATCH 64
#define H 1024
#define W 1024
#define RPB 64                 // rows per block strip (== wavefront size)
#define STRIPS (H / RPB)       // 16
#define NT 256                 // threads per block (W/4)
#define TSHIFT 19              // t = m2_bits >> 19 (exponent + 4 mantissa bits)
#define TLO 1536u              // live t window [1536, 2176): m^2 in [2^-13, 512)
#define NB 640                 // words per region window
#define NFLAT (4 * NB)         // 2560 flat bins for regions 0..3
#define NWORDS 4736            // LDS words: widx = q*640 + t in [1536, 4736)
#define INVN (1.0f / (float)(H * W))

// One row of 4 pixels. FIRST = image row 0 (gy forced 0; gx<0 -> "no-bin" region 4).
// Region id q' = (sign(gy)<<1) | sign(gx); finalize relabels to reference bins.
template<bool FIRST>
__device__ __forceinline__ void do_row(const float4 cur, const float4 pv4, float left,
                                       float eps, float& mx2, unsigned int* shHist) {
    float px[4] = {cur.x, cur.y, cur.z, cur.w};
    float pl[4] = {left, cur.x, cur.y, cur.z};
    float pv[4] = {pv4.x, pv4.y, pv4.z, pv4.w};
    #pragma unroll
    for (int j = 0; j < 4; ++j) {
        float gx = px[j] - pl[j];
        float gy = FIRST ? 0.0f : (px[j] - pv[j]);
        float m2 = __builtin_fmaf(gx, gx, __builtin_fmaf(gy, gy, eps));
        mx2 = fmaxf(mx2, m2);
        unsigned int sxp = __float_as_uint(gx) >> 31;
        unsigned int q;
        if (FIRST) {
            q = sxp ? 4u : 0u;      // gy==0: gx>=0 -> angle 0 (q'=0); gx<0 -> pi -> no-bin
        } else {
            unsigned int sy = __float_as_uint(gy) >> 31;
            q = (sy << 1) | sxp;
        }
        unsigned int widx = q * NB + (__float_as_uint(m2) >> TSHIFT);
        atomicAdd(&shHist[widx], 1u);   // widx in [1536, 4736), no clamp needed
    }
}

// ---------------- Pass 1 + inline last-block finalize ----------------
__global__ __launch_bounds__(NT) void pass1_kernel(const float* __restrict__ x,
                                                   unsigned int* __restrict__ hist,
                                                   unsigned int* __restrict__ hist4,
                                                   float* __restrict__ smax,
                                                   unsigned int* __restrict__ done,
                                                   float* __restrict__ out) {
    const int strip = blockIdx.x;
    const int b = blockIdx.y;
    const int tid = threadIdx.x;
    const int wave = tid >> 6;
    const int lane = tid & 63;
    const int seg0 = wave << 8;           // wave's 256-col segment base
    const int col = seg0 + (lane << 2);
    const float* img = x + (size_t)b * H * W;
    const int r0 = strip * RPB;
    const int rend = r0 + RPB;
    const float eps = 1e-8f;

    __shared__ unsigned int shHist[NWORDS];
    __shared__ float shMax[4];
    __shared__ int shLast;
    __shared__ float shS[4];
    __shared__ float shRed[4][9];
    __shared__ float shMean;

    for (int i = TLO + tid; i < NWORDS; i += NT) shHist[i] = 0u;
    __syncthreads();

    // Preload this wave's left-boundary column: lane l holds img[r0+l][seg0-1].
    float lb_all = 0.f;
    if (seg0 > 0) lb_all = img[(size_t)(r0 + lane) * W + (seg0 - 1)];

    float mx2 = 0.f;
    float4 prev;
    int r = r0;

    if (r0 == 0) {
        float4 cur0 = *(const float4*)(img + col);
        float sw = __shfl_up(cur0.w, 1, 64);
        float bb = __shfl(lb_all, 0, 64);
        float left = (lane == 0) ? ((seg0 == 0) ? cur0.x : bb) : sw;
        do_row<true>(cur0, cur0, left, eps, mx2, shHist);
        prev = cur0;
        r = 1;
    } else {
        prev = *(const float4*)(img + (size_t)(r0 - 1) * W + col);
    }

    // 2-deep row prefetch
    float4 pf0 = *(const float4*)(img + (size_t)r * W + col);
    float4 pf1 = *(const float4*)(img + (size_t)(r + 1) * W + col);

    if ((rend - r) & 1) {           // odd remaining rows (strip 0 after peel)
        float4 c0 = pf0;
        pf0 = pf1;
        if (r + 2 < rend) pf1 = *(const float4*)(img + (size_t)(r + 2) * W + col);
        float sw = __shfl_up(c0.w, 1, 64);
        float bb = __shfl(lb_all, r - r0, 64);
        float left = (lane == 0) ? ((seg0 == 0) ? c0.x : bb) : sw;
        do_row<false>(c0, prev, left, eps, mx2, shHist);
        prev = c0;
        ++r;
    }

    for (; r < rend; r += 2) {      // 2 rows/iter, prefetch 2 ahead
        float4 c0 = pf0, c1 = pf1;
        if (r + 3 < rend) {
            pf0 = *(const float4*)(img + (size_t)(r + 2) * W + col);
            pf1 = *(const float4*)(img + (size_t)(r + 3) * W + col);
        }
        float sw0 = __shfl_up(c0.w, 1, 64);
        float bb0 = __shfl(lb_all, r - r0, 64);
        float left0 = (lane == 0) ? ((seg0 == 0) ? c0.x : bb0) : sw0;
        float sw1 = __shfl_up(c1.w, 1, 64);
        float bb1 = __shfl(lb_all, r + 1 - r0, 64);
        float left1 = (lane == 0) ? ((seg0 == 0) ? c1.x : bb1) : sw1;
        do_row<false>(c0, prev, left0, eps, mx2, shHist);
        do_row<false>(c1, c0, left1, eps, mx2, shHist);
        prev = c1;
    }

    // per-strip max(m^2)
    #pragma unroll
    for (int o = 32; o > 0; o >>= 1)
        mx2 = fmaxf(mx2, __shfl_down(mx2, o, 64));
    if (lane == 0) shMax[wave] = mx2;
    __syncthreads();   // shHist atomics + shMax complete
    if (tid == 0)
        smax[b * STRIPS + strip] =
            fmaxf(fmaxf(shMax[0], shMax[1]), fmaxf(shMax[2], shMax[3]));

    // flush regions 0..3 (coalesced); strip 0 also flushes region 4
    unsigned int* gh = hist + (size_t)(b * STRIPS + strip) * NFLAT;
    for (int i = tid; i < NFLAT; i += NT) gh[i] = shHist[TLO + i];
    if (strip == 0) {
        unsigned int* g4 = hist4 + (size_t)b * NB;
        for (int i = tid; i < NB; i += NT) g4[i] = shHist[4096 + i];
    }

    // ---- last-block-done: publish, then one block per image finalizes ----
    __threadfence();
    __syncthreads();
    if (tid == 0) {
        unsigned int old = atomicAdd(&done[b], 1u);
        shLast = (old == STRIPS - 1);
    }
    __syncthreads();
    if (!shLast) return;
    __threadfence();   // acquire: other blocks' hist/smax stores now visible

    // ---- inline finalize for image b ----
    const int ln = tid & 63, wv = tid >> 6;

    // strip-sum: thread owns flat bins {k*256+tid}, coalesced reads
    unsigned int acc[10];
    #pragma unroll
    for (int k = 0; k < 10; ++k) acc[k] = 0u;
    const unsigned int* basep = hist + (size_t)b * STRIPS * NFLAT;
    for (int s = 0; s < STRIPS; ++s) {
        const unsigned int* src = basep + (size_t)s * NFLAT;
        #pragma unroll
        for (int k = 0; k < 10; ++k) acc[k] += src[k * NT + tid];
    }

    // bin centers in m-space; region r and t recovered from flat index
    float mc[10];
    int tt[10], rr[10];
    #pragma unroll
    for (int k = 0; k < 10; ++k) {
        int idx = k * NT + tid;
        int rg = idx / NB;
        int t = idx - rg * NB + (int)TLO;
        rr[k] = rg; tt[k] = t;
        float lo = __uint_as_float((unsigned int)t << TSHIFT);
        float hi = __uint_as_float((unsigned int)(t + 1) << TSHIFT);
        mc[k] = 0.5f * (sqrtf(lo) + sqrtf(hi));
    }

    // total sum of magnitudes (incl. region 4) -> mean
    float sv = 0.f;
    #pragma unroll
    for (int k = 0; k < 10; ++k) sv += (float)acc[k] * mc[k];
    const unsigned int* g4 = hist4 + (size_t)b * NB;
    for (int i = tid; i < NB; i += NT) {
        unsigned int t = TLO + (unsigned int)i;
        float lo = __uint_as_float(t << TSHIFT);
        float hi = __uint_as_float((t + 1) << TSHIFT);
        sv += (float)g4[i] * (0.5f * (sqrtf(lo) + sqrtf(hi)));
    }
    #pragma unroll
    for (int o = 32; o > 0; o >>= 1) sv += __shfl_down(sv, o, 64);
    if (ln == 0) shS[wv] = sv;

    float vm = 0.f;
    if (tid < STRIPS) vm = smax[b * STRIPS + tid];
    if (tid < 64) {
        #pragma unroll
        for (int o = 32; o > 0; o >>= 1)
            vm = fmaxf(vm, __shfl_down(vm, o, 64));
    }
    __syncthreads();
    if (tid == 0) {
        float mean = (shS[0] + shS[1] + shS[2] + shS[3]) * INVN;
        shMean = mean;
        out[b * 7 + 1] = mean;          // edge_strength
        out[b * 7 + 2] = sqrtf(vm);     // edge_max (exact)
    }
    __syncthreads();
    const float mean = shMean;

    // threshold bin + m-space interpolation fraction
    int tmean = (int)(__float_as_uint(mean * mean) >> TSHIFT);
    float lok = sqrtf(__uint_as_float((unsigned int)tmean << TSHIFT));
    float hik = sqrtf(__uint_as_float((unsigned int)(tmean + 1) << TSHIFT));
    float frac = fminf(fmaxf((mean - lok) / (hik - lok), 0.f), 1.f);

    // per-region {sum m, count} + density count; static accumulator indices
    float v[9];
    #pragma unroll
    for (int k = 0; k < 9; ++k) v[k] = 0.f;
    #pragma unroll
    for (int k = 0; k < 10; ++k) {
        int rg = rr[k], t = tt[k];
        float h = (float)acc[k];
        float hm = h * mc[k];
        v[0] += (rg == 0) ? hm : 0.f;  v[4] += (rg == 0) ? h : 0.f;
        v[1] += (rg == 1) ? hm : 0.f;  v[5] += (rg == 1) ? h : 0.f;
        v[2] += (rg == 2) ? hm : 0.f;  v[6] += (rg == 2) ? h : 0.f;
        v[3] += (rg == 3) ? hm : 0.f;  v[7] += (rg == 3) ? h : 0.f;
        v[8] += (t > tmean) ? h : ((t == tmean) ? h * (1.f - frac) : 0.f);
    }
    for (int i = tid; i < NB; i += NT) {    // region 4 joins density only
        int t = (int)TLO + i;
        float h = (float)g4[i];
        v[8] += (t > tmean) ? h : ((t == tmean) ? h * (1.f - frac) : 0.f);
    }
    #pragma unroll
    for (int k = 0; k < 9; ++k) {
        #pragma unroll
        for (int o = 32; o > 0; o >>= 1) v[k] += __shfl_down(v[k], o, 64);
    }
    if (ln == 0) {
        #pragma unroll
        for (int k = 0; k < 9; ++k) shRed[wv][k] = v[k];
    }
    __syncthreads();
    if (tid == 0) {
        float t[9];
        #pragma unroll
        for (int k = 0; k < 9; ++k)
            t[k] = shRed[0][k] + shRed[1][k] + shRed[2][k] + shRed[3][k];
        out[b * 7 + 0] = t[8] * INVN;               // edge_density
        // q' -> reference bin: q'3->bin0, q'2->bin1, q'0->bin2, q'1->bin3
        out[b * 7 + 3] = t[3] / (t[7] + 1e-8f);
        out[b * 7 + 4] = t[2] / (t[6] + 1e-8f);
        out[b * 7 + 5] = t[0] / (t[4] + 1e-8f);
        out[b * 7 + 6] = t[1] / (t[5] + 1e-8f);
    }
}

extern "C" void kernel_launch(void* const* d_in, const int* in_sizes, int n_in,
                              void* d_out, int out_size, void* d_ws, size_t ws_size,
                              hipStream_t stream) {
    const float* x = (const float*)d_in[0];
    float* out = (float*)d_out;

    unsigned int* hist = (unsigned int*)d_ws;                        // 64*16*2560 u32 ~ 10.5 MB
    unsigned int* hist4 = hist + (size_t)BATCH * STRIPS * NFLAT;     // 64*640 u32
    float* smax = (float*)(hist4 + (size_t)BATCH * NB);              // 64*16 floats
    unsigned int* done = (unsigned int*)(smax + BATCH * STRIPS);     // 64 u32

    hipMemsetAsync(done, 0, BATCH * sizeof(unsigned int), stream);

    dim3 grid(STRIPS, BATCH);
    pass1_kernel<<<grid, NT, 0, stream>>>(x, hist, hist4, smax, done, out);
}

// Round 8
// 62.054 us; speedup vs baseline: 3.0448x; 3.0448x over previous
//
#include <hip/hip_runtime.h>

#define BATCH 64
#define H 1024
#define W 1024
#define RPB 64                 // rows per block strip (== wavefront size)
#define STRIPS (H / RPB)       // 16
#define NT 256                 // threads per block (W/4)
#define TSHIFT 19              // t = m2_bits >> 19 (exponent + 4 mantissa bits)
#define TLO 1600               // flush/zero window base
#define NBS 648                // region stride in words (648 % 32 == 8 -> bank stagger)
#define TBASE 1605             // min live t (m2 >= 1e-8)
#define NWORDS 4928            // flush window end (covers region 4 max 4767)
#define NFL (NWORDS - TLO)     // 3328 = 13*256 words flushed per strip
#define KITERS (NFL / NT)      // 13
#define INVN (1.0f / (float)(H * W))

// One row of 4 pixels. FIRST = image row 0 (gy forced 0; gx<0 -> "no-bin" region 4).
// Region id q' = (sign(gy)<<1) | sign(gx); finalize relabels to reference bins.
template<bool FIRST>
__device__ __forceinline__ void do_row(const float4 cur, const float4 pv4, float left,
                                       float eps, float& mx2, unsigned int* shWin) {
    float px[4] = {cur.x, cur.y, cur.z, cur.w};
    float pl[4] = {left, cur.x, cur.y, cur.z};
    float pv[4] = {pv4.x, pv4.y, pv4.z, pv4.w};
    #pragma unroll
    for (int j = 0; j < 4; ++j) {
        float gx = px[j] - pl[j];
        float gy = FIRST ? 0.0f : (px[j] - pv[j]);
        float m2 = __builtin_fmaf(gx, gx, __builtin_fmaf(gy, gy, eps));
        mx2 = fmaxf(mx2, m2);
        unsigned int sxp = __float_as_uint(gx) >> 31;
        unsigned int q;
        if (FIRST) {
            q = sxp ? 4u : 0u;   // gy==0: gx>=0 -> angle 0 (q'=0); gx<0 -> pi -> no-bin
        } else {
            unsigned int sy = __float_as_uint(gy) >> 31;
            q = (sy << 1) | sxp;
        }
        unsigned int widx = q * NBS + (__float_as_uint(m2) >> TSHIFT);
        atomicAdd(&shWin[widx - TLO], 1u);   // widx in [1605, 4768) -> in-window
    }
}

// ---------------- Pass 1: per-strip 5-region histogram + max(m^2) ----------------
__global__ __launch_bounds__(NT) void pass1_kernel(const float* __restrict__ x,
                                                   unsigned int* __restrict__ hist,
                                                   float* __restrict__ smax) {
    const int strip = blockIdx.x;
    const int b = blockIdx.y;
    const int tid = threadIdx.x;
    const int wave = tid >> 6;
    const int lane = tid & 63;
    const int seg0 = wave << 8;           // wave's 256-col segment base
    const int col = seg0 + (lane << 2);
    const float* img = x + (size_t)b * H * W;
    const int r0 = strip * RPB;
    const int rend = r0 + RPB;
    const float eps = 1e-8f;

    __shared__ unsigned int shWin[NFL];
    __shared__ float shMax[4];

    #pragma unroll
    for (int k = 0; k < KITERS; ++k) shWin[k * NT + tid] = 0u;
    __syncthreads();

    // Preload this wave's left-boundary column: lane l holds img[r0+l][seg0-1].
    float lb_all = 0.f;
    if (seg0 > 0) lb_all = img[(size_t)(r0 + lane) * W + (seg0 - 1)];

    float mx2 = 0.f;
    float4 prev;
    int r = r0;

    if (r0 == 0) {
        float4 cur0 = *(const float4*)(img + col);
        float sw = __shfl_up(cur0.w, 1, 64);
        float bb = __shfl(lb_all, 0, 64);
        float left = (lane == 0) ? ((seg0 == 0) ? cur0.x : bb) : sw;
        do_row<true>(cur0, cur0, left, eps, mx2, shWin);
        prev = cur0;
        r = 1;
    } else {
        prev = *(const float4*)(img + (size_t)(r0 - 1) * W + col);
    }

    // 4-deep row prefetch
    float4 pf0 = *(const float4*)(img + (size_t)r * W + col);
    float4 pf1 = *(const float4*)(img + (size_t)(r + 1) * W + col);
    float4 pf2 = *(const float4*)(img + (size_t)(r + 2) * W + col);
    float4 pf3 = *(const float4*)(img + (size_t)(r + 3) * W + col);

    if ((rend - r) & 1) {           // odd remaining rows (strip 0 after peel)
        float4 c0 = pf0;
        pf0 = pf1; pf1 = pf2; pf2 = pf3;
        if (r + 4 < rend) pf3 = *(const float4*)(img + (size_t)(r + 4) * W + col);
        float sw = __shfl_up(c0.w, 1, 64);
        float bb = __shfl(lb_all, r - r0, 64);
        float left = (lane == 0) ? ((seg0 == 0) ? c0.x : bb) : sw;
        do_row<false>(c0, prev, left, eps, mx2, shWin);
        prev = c0;
        ++r;
    }

    for (; r < rend; r += 2) {      // 2 rows/iter, pipeline 4 rows deep
        float4 c0 = pf0, c1 = pf1;
        pf0 = pf2; pf1 = pf3;
        if (r + 5 < rend) {
            pf2 = *(const float4*)(img + (size_t)(r + 4) * W + col);
            pf3 = *(const float4*)(img + (size_t)(r + 5) * W + col);
        }
        float sw0 = __shfl_up(c0.w, 1, 64);
        float bb0 = __shfl(lb_all, r - r0, 64);
        float left0 = (lane == 0) ? ((seg0 == 0) ? c0.x : bb0) : sw0;
        float sw1 = __shfl_up(c1.w, 1, 64);
        float bb1 = __shfl(lb_all, r + 1 - r0, 64);
        float left1 = (lane == 0) ? ((seg0 == 0) ? c1.x : bb1) : sw1;
        do_row<false>(c0, prev, left0, eps, mx2, shWin);
        do_row<false>(c1, c0, left1, eps, mx2, shWin);
        prev = c1;
    }

    // per-strip max(m^2): wave reduce -> cross-wave via LDS -> plain store
    #pragma unroll
    for (int o = 32; o > 0; o >>= 1)
        mx2 = fmaxf(mx2, __shfl_down(mx2, o, 64));
    if (lane == 0) shMax[wave] = mx2;
    __syncthreads();   // shWin atomics + shMax complete
    if (tid == 0)
        smax[b * STRIPS + strip] =
            fmaxf(fmaxf(shMax[0], shMax[1]), fmaxf(shMax[2], shMax[3]));

    // flush whole window (coalesced plain stores, no atomics, no fences)
    unsigned int* gh = hist + (size_t)(b * STRIPS + strip) * NFL;
    #pragma unroll
    for (int k = 0; k < KITERS; ++k) gh[k * NT + tid] = shWin[k * NT + tid];
}

// ---------------- Finalize: one block per image, coalesced strip-sum ----------------
__global__ __launch_bounds__(NT) void finalize_kernel(const unsigned int* __restrict__ hist,
                                                      const float* __restrict__ smax,
                                                      float* __restrict__ out) {
    const int b = blockIdx.x;
    const int tid = threadIdx.x;
    const int wv = tid >> 6, ln = tid & 63;
    __shared__ float shRed[4][9];
    __shared__ float shS[4];
    __shared__ float shMean;

    // sum the 16 per-strip windows; thread owns words {k*256+tid} (coalesced reads)
    unsigned int acc[KITERS];
    #pragma unroll
    for (int k = 0; k < KITERS; ++k) acc[k] = 0u;
    const unsigned int* basep = hist + (size_t)b * STRIPS * NFL;
    for (int s = 0; s < STRIPS; ++s) {
        const unsigned int* src = basep + (size_t)s * NFL;
        #pragma unroll
        for (int k = 0; k < KITERS; ++k) acc[k] += src[k * NT + tid];
    }

    // recover region + t; bin centers in m-space. Gap/pad words have acc==0.
    float mc[KITERS];
    int tt[KITERS], rr[KITERS];
    #pragma unroll
    for (int k = 0; k < KITERS; ++k) {
        int w = k * NT + tid + TLO;
        int d = w - TBASE; d = d < 0 ? 0 : d;
        int q = d / NBS;                       // magic-mul division by 648
        int t = w - q * NBS;
        rr[k] = q; tt[k] = t;
        float lo = __uint_as_float((unsigned int)t << TSHIFT);
        float hi = __uint_as_float((unsigned int)(t + 1) << TSHIFT);
        mc[k] = 0.5f * (sqrtf(lo) + sqrtf(hi));
    }

    // total sum of magnitudes (all regions) -> mean ; strip-max -> edge_max
    float sv = 0.f;
    #pragma unroll
    for (int k = 0; k < KITERS; ++k) sv += (float)acc[k] * mc[k];
    #pragma unroll
    for (int o = 32; o > 0; o >>= 1) sv += __shfl_down(sv, o, 64);
    if (ln == 0) shS[wv] = sv;

    float vm = 0.f;
    if (tid < STRIPS) vm = smax[b * STRIPS + tid];
    if (tid < 64) {
        #pragma unroll
        for (int o = 32; o > 0; o >>= 1)
            vm = fmaxf(vm, __shfl_down(vm, o, 64));
    }
    __syncthreads();
    if (tid == 0) {
        float mean = (shS[0] + shS[1] + shS[2] + shS[3]) * INVN;
        shMean = mean;
        out[b * 7 + 1] = mean;          // edge_strength
        out[b * 7 + 2] = sqrtf(vm);     // edge_max (exact)
    }
    __syncthreads();
    const float mean = shMean;

    // threshold bin + m-space interpolation fraction
    int tmean = (int)(__float_as_uint(mean * mean) >> TSHIFT);
    float lok = sqrtf(__uint_as_float((unsigned int)tmean << TSHIFT));
    float hik = sqrtf(__uint_as_float((unsigned int)(tmean + 1) << TSHIFT));
    float frac = fminf(fmaxf((mean - lok) / (hik - lok), 0.f), 1.f);

    // per-region {sum m, count} + density count; static accumulator indices
    float v[9];
    #pragma unroll
    for (int k = 0; k < 9; ++k) v[k] = 0.f;
    #pragma unroll
    for (int k = 0; k < KITERS; ++k) {
        int rg = rr[k], t = tt[k];
        float h = (float)acc[k];
        float hm = h * mc[k];
        v[0] += (rg == 0) ? hm : 0.f;  v[4] += (rg == 0) ? h : 0.f;
        v[1] += (rg == 1) ? hm : 0.f;  v[5] += (rg == 1) ? h : 0.f;
        v[2] += (rg == 2) ? hm : 0.f;  v[6] += (rg == 2) ? h : 0.f;
        v[3] += (rg == 3) ? hm : 0.f;  v[7] += (rg == 3) ? h : 0.f;
        v[8] += (t > tmean) ? h : ((t == tmean) ? h * (1.f - frac) : 0.f);  // all regions
    }
    #pragma unroll
    for (int k = 0; k < 9; ++k) {
        #pragma unroll
        for (int o = 32; o > 0; o >>= 1) v[k] += __shfl_down(v[k], o, 64);
    }
    if (ln == 0) {
        #pragma unroll
        for (int k = 0; k < 9; ++k) shRed[wv][k] = v[k];
    }
    __syncthreads();
    if (tid == 0) {
        float t[9];
        #pragma unroll
        for (int k = 0; k < 9; ++k)
            t[k] = shRed[0][k] + shRed[1][k] + shRed[2][k] + shRed[3][k];
        out[b * 7 + 0] = t[8] * INVN;               // edge_density
        // q' -> reference bin: q'3->bin0, q'2->bin1, q'0->bin2, q'1->bin3
        out[b * 7 + 3] = t[3] / (t[7] + 1e-8f);
        out[b * 7 + 4] = t[2] / (t[6] + 1e-8f);
        out[b * 7 + 5] = t[0] / (t[4] + 1e-8f);
        out[b * 7 + 6] = t[1] / (t[5] + 1e-8f);
    }
}

extern "C" void kernel_launch(void* const* d_in, const int* in_sizes, int n_in,
                              void* d_out, int out_size, void* d_ws, size_t ws_size,
                              hipStream_t stream) {
    const float* x = (const float*)d_in[0];
    float* out = (float*)d_out;

    unsigned int* hist = (unsigned int*)d_ws;                    // 64*16*3328 u32 ~ 13.6 MB
    float* smax = (float*)(hist + (size_t)BATCH * STRIPS * NFL); // 64*16 floats

    dim3 grid(STRIPS, BATCH);
    pass1_kernel<<<grid, NT, 0, stream>>>(x, hist, smax);
    finalize_kernel<<<BATCH, NT, 0, stream>>>(hist, smax, out);
}

// Round 9
// 58.395 us; speedup vs baseline: 3.2356x; 1.0627x over previous
//
#include <hip/hip_runtime.h>

#define BATCH 64
#define H 1024
#define W 1024
#define RPB 64                 // rows per block strip (== wavefront size)
#define STRIPS (H / RPB)       // 16
#define NT 256                 // threads per block (W/4)
#define TSHIFT 19              // t = m2_bits >> 19 (exponent + 4 mantissa bits)
#define NBS 648                // region stride in words (648 % 32 == 8 -> bank stagger)
#define WBASE 1605             // min live widx: t(m2=1e-8) = 1605, q=0
#define NLDS 3328              // LDS words (13*256), covers widx [1605, 4933)
#define NFL 2560               // flushed words per strip: regions 0..3 (widx < 4165)
#define N4 640                 // region-4 flush words (strip 0 only), widx [4165, 4805)
#define INVN (1.0f / (float)(H * W))

// One row of 4 pixels. FIRST = image row 0 (gy forced 0; gx<0 -> "no-bin" region 4).
// Region id q' = (sign(gy)<<1) | sign(gx); finalize relabels to reference bins.
template<bool FIRST>
__device__ __forceinline__ void do_row(const float4 cur, const float4 pv4, float left,
                                       float eps, float& mx2, unsigned int* shWin) {
    float px[4] = {cur.x, cur.y, cur.z, cur.w};
    float pl[4] = {left, cur.x, cur.y, cur.z};
    float pv[4] = {pv4.x, pv4.y, pv4.z, pv4.w};
    #pragma unroll
    for (int j = 0; j < 4; ++j) {
        float gx = px[j] - pl[j];
        float gy = FIRST ? 0.0f : (px[j] - pv[j]);
        float m2 = __builtin_fmaf(gx, gx, __builtin_fmaf(gy, gy, eps));
        mx2 = fmaxf(mx2, m2);
        unsigned int sxp = __float_as_uint(gx) >> 31;
        unsigned int q;
        if (FIRST) {
            q = sxp ? 4u : 0u;   // gy==0: gx>=0 -> angle 0 (q'=0); gx<0 -> pi -> no-bin
        } else {
            unsigned int sy = __float_as_uint(gy) >> 31;
            q = (sy << 1) | sxp;
        }
        unsigned int widx = q * NBS + (__float_as_uint(m2) >> TSHIFT);
        atomicAdd(&shWin[widx - WBASE], 1u);   // widx in [1605, 4768) -> in-window
    }
}

// ---------------- Pass 1: per-strip 5-region histogram + max(m^2) ----------------
__global__ __launch_bounds__(NT) void pass1_kernel(const float* __restrict__ x,
                                                   unsigned int* __restrict__ hist,
                                                   unsigned int* __restrict__ hist4,
                                                   float* __restrict__ smax) {
    const int strip = blockIdx.x;
    const int b = blockIdx.y;
    const int tid = threadIdx.x;
    const int wave = tid >> 6;
    const int lane = tid & 63;
    const int seg0 = wave << 8;           // wave's 256-col segment base
    const int col = seg0 + (lane << 2);
    const float* img = x + (size_t)b * H * W;
    const int r0 = strip * RPB;
    const int rend = r0 + RPB;
    const float eps = 1e-8f;

    __shared__ unsigned int shWin[NLDS];
    __shared__ float shMax[4];

    #pragma unroll
    for (int k = 0; k < NLDS / NT; ++k) shWin[k * NT + tid] = 0u;
    __syncthreads();

    // Preload this wave's left-boundary column: lane l holds img[r0+l][seg0-1].
    float lb_all = 0.f;
    if (seg0 > 0) lb_all = img[(size_t)(r0 + lane) * W + (seg0 - 1)];

    float mx2 = 0.f;
    float4 prev;
    int r = r0;

    if (r0 == 0) {
        float4 cur0 = *(const float4*)(img + col);
        float sw = __shfl_up(cur0.w, 1, 64);
        float bb = __shfl(lb_all, 0, 64);
        float left = (lane == 0) ? ((seg0 == 0) ? cur0.x : bb) : sw;
        do_row<true>(cur0, cur0, left, eps, mx2, shWin);
        prev = cur0;
        r = 1;
    } else {
        prev = *(const float4*)(img + (size_t)(r0 - 1) * W + col);
    }

    // 2-deep row prefetch
    float4 pf0 = *(const float4*)(img + (size_t)r * W + col);
    float4 pf1 = *(const float4*)(img + (size_t)(r + 1) * W + col);

    if ((rend - r) & 1) {           // odd remaining rows (strip 0 after peel)
        float4 c0 = pf0;
        pf0 = pf1;
        if (r + 2 < rend) pf1 = *(const float4*)(img + (size_t)(r + 2) * W + col);
        float sw = __shfl_up(c0.w, 1, 64);
        float bb = __shfl(lb_all, r - r0, 64);
        float left = (lane == 0) ? ((seg0 == 0) ? c0.x : bb) : sw;
        do_row<false>(c0, prev, left, eps, mx2, shWin);
        prev = c0;
        ++r;
    }

    for (; r < rend; r += 2) {      // 2 rows/iter, prefetch 2 ahead
        float4 c0 = pf0, c1 = pf1;
        if (r + 3 < rend) {
            pf0 = *(const float4*)(img + (size_t)(r + 2) * W + col);
            pf1 = *(const float4*)(img + (size_t)(r + 3) * W + col);
        }
        float sw0 = __shfl_up(c0.w, 1, 64);
        float bb0 = __shfl(lb_all, r - r0, 64);
        float left0 = (lane == 0) ? ((seg0 == 0) ? c0.x : bb0) : sw0;
        float sw1 = __shfl_up(c1.w, 1, 64);
        float bb1 = __shfl(lb_all, r + 1 - r0, 64);
        float left1 = (lane == 0) ? ((seg0 == 0) ? c1.x : bb1) : sw1;
        do_row<false>(c0, prev, left0, eps, mx2, shWin);
        do_row<false>(c1, c0, left1, eps, mx2, shWin);
        prev = c1;
    }

    // per-strip max(m^2): wave reduce -> cross-wave via LDS -> plain store
    #pragma unroll
    for (int o = 32; o > 0; o >>= 1)
        mx2 = fmaxf(mx2, __shfl_down(mx2, o, 64));
    if (lane == 0) shMax[wave] = mx2;
    __syncthreads();   // shWin atomics + shMax complete
    if (tid == 0)
        smax[b * STRIPS + strip] =
            fmaxf(fmaxf(shMax[0], shMax[1]), fmaxf(shMax[2], shMax[3]));

    // flush regions 0..3 (coalesced plain stores); strip 0 also flushes region 4
    unsigned int* gh = hist + (size_t)(b * STRIPS + strip) * NFL;
    #pragma unroll
    for (int k = 0; k < NFL / NT; ++k) gh[k * NT + tid] = shWin[k * NT + tid];
    if (strip == 0) {
        unsigned int* g4 = hist4 + (size_t)b * N4;
        #pragma unroll
        for (int k = 0; k < N4 / NT; ++k) g4[k * NT + tid] = shWin[NFL + k * NT + tid];
        if (tid < N4 - (N4 / NT) * NT) g4[(N4 / NT) * NT + tid] = shWin[NFL + (N4 / NT) * NT + tid];
    }
}

// ---------------- Finalize: one block per image, coalesced strip-sum ----------------
__global__ __launch_bounds__(NT) void finalize_kernel(const unsigned int* __restrict__ hist,
                                                      const unsigned int* __restrict__ hist4,
                                                      const float* __restrict__ smax,
                                                      float* __restrict__ out) {
    const int b = blockIdx.x;
    const int tid = threadIdx.x;
    const int wv = tid >> 6, ln = tid & 63;
    __shared__ float shRed[4][9];
    __shared__ float shS[4];
    __shared__ float shMean;

    // sum the 16 per-strip windows; thread owns words {k*256+tid} (coalesced reads)
    unsigned int acc[NFL / NT];
    #pragma unroll
    for (int k = 0; k < NFL / NT; ++k) acc[k] = 0u;
    const unsigned int* basep = hist + (size_t)b * STRIPS * NFL;
    for (int s = 0; s < STRIPS; ++s) {
        const unsigned int* src = basep + (size_t)s * NFL;
        #pragma unroll
        for (int k = 0; k < NFL / NT; ++k) acc[k] += src[k * NT + tid];
    }

    // recover region + t from flat f = widx - WBASE: q = f/648 (live dt < 571 < 648)
    float mc[NFL / NT];
    int tt[NFL / NT], rr[NFL / NT];
    #pragma unroll
    for (int k = 0; k < NFL / NT; ++k) {
        int f = k * NT + tid;
        int q = f / NBS;
        int t = f - q * NBS + WBASE;
        rr[k] = q; tt[k] = t;
        float lo = __uint_as_float((unsigned int)t << TSHIFT);
        float hi = __uint_as_float((unsigned int)(t + 1) << TSHIFT);
        mc[k] = 0.5f * (sqrtf(lo) + sqrtf(hi));
    }

    // total sum of magnitudes (regions 0..3 + region 4) -> mean
    float sv = 0.f;
    #pragma unroll
    for (int k = 0; k < NFL / NT; ++k) sv += (float)acc[k] * mc[k];

    const unsigned int* g4 = hist4 + (size_t)b * N4;
    float d4 = 0.f;         // region-4 contributions gathered per-thread
    float s4 = 0.f;
    unsigned int h4[3];     // N4/NT = 2 full + partial third
    int t4[3];
    #pragma unroll
    for (int k = 0; k < 3; ++k) { h4[k] = 0u; t4[k] = WBASE; }
    #pragma unroll
    for (int k = 0; k < 3; ++k) {
        int i = k * NT + tid;
        if (i < N4) {
            h4[k] = g4[i];
            t4[k] = (NFL + i) - 4 * NBS + WBASE;   // widx - 4*648
        }
    }
    #pragma unroll
    for (int k = 0; k < 3; ++k) {
        int t = t4[k];
        float lo = __uint_as_float((unsigned int)t << TSHIFT);
        float hi = __uint_as_float((unsigned int)(t + 1) << TSHIFT);
        s4 += (float)h4[k] * (0.5f * (sqrtf(lo) + sqrtf(hi)));
    }
    sv += s4;
    #pragma unroll
    for (int o = 32; o > 0; o >>= 1) sv += __shfl_down(sv, o, 64);
    if (ln == 0) shS[wv] = sv;

    float vm = 0.f;
    if (tid < STRIPS) vm = smax[b * STRIPS + tid];
    if (tid < 64) {
        #pragma unroll
        for (int o = 32; o > 0; o >>= 1)
            vm = fmaxf(vm, __shfl_down(vm, o, 64));
    }
    __syncthreads();
    if (tid == 0) {
        float mean = (shS[0] + shS[1] + shS[2] + shS[3]) * INVN;
        shMean = mean;
        out[b * 7 + 1] = mean;          // edge_strength
        out[b * 7 + 2] = sqrtf(vm);     // edge_max (exact)
    }
    __syncthreads();
    const float mean = shMean;

    // threshold bin + m-space interpolation fraction
    int tmean = (int)(__float_as_uint(mean * mean) >> TSHIFT);
    float lok = sqrtf(__uint_as_float((unsigned int)tmean << TSHIFT));
    float hik = sqrtf(__uint_as_float((unsigned int)(tmean + 1) << TSHIFT));
    float frac = fminf(fmaxf((mean - lok) / (hik - lok), 0.f), 1.f);

    // per-region {sum m, count} + density count; static accumulator indices
    float v[9];
    #pragma unroll
    for (int k = 0; k < 9; ++k) v[k] = 0.f;
    #pragma unroll
    for (int k = 0; k < NFL / NT; ++k) {
        int rg = rr[k], t = tt[k];
        float h = (float)acc[k];
        float hm = h * mc[k];
        v[0] += (rg == 0) ? hm : 0.f;  v[4] += (rg == 0) ? h : 0.f;
        v[1] += (rg == 1) ? hm : 0.f;  v[5] += (rg == 1) ? h : 0.f;
        v[2] += (rg == 2) ? hm : 0.f;  v[6] += (rg == 2) ? h : 0.f;
        v[3] += (rg == 3) ? hm : 0.f;  v[7] += (rg == 3) ? h : 0.f;
        v[8] += (t > tmean) ? h : ((t == tmean) ? h * (1.f - frac) : 0.f);
    }
    #pragma unroll
    for (int k = 0; k < 3; ++k) {      // region 4 joins density only
        int t = t4[k];
        float h = (float)h4[k];
        v[8] += (t > tmean) ? h : ((t == tmean) ? h * (1.f - frac) : 0.f);
    }
    #pragma unroll
    for (int k = 0; k < 9; ++k) {
        #pragma unroll
        for (int o = 32; o > 0; o >>= 1) v[k] += __shfl_down(v[k], o, 64);
    }
    if (ln == 0) {
        #pragma unroll
        for (int k = 0; k < 9; ++k) shRed[wv][k] = v[k];
    }
    __syncthreads();
    if (tid == 0) {
        float t[9];
        #pragma unroll
        for (int k = 0; k < 9; ++k)
            t[k] = shRed[0][k] + shRed[1][k] + shRed[2][k] + shRed[3][k];
        out[b * 7 + 0] = t[8] * INVN;               // edge_density
        // q' -> reference bin: q'3->bin0, q'2->bin1, q'0->bin2, q'1->bin3
        out[b * 7 + 3] = t[3] / (t[7] + 1e-8f);
        out[b * 7 + 4] = t[2] / (t[6] + 1e-8f);
        out[b * 7 + 5] = t[0] / (t[4] + 1e-8f);
        out[b * 7 + 6] = t[1] / (t[5] + 1e-8f);
    }
}

extern "C" void kernel_launch(void* const* d_in, const int* in_sizes, int n_in,
                              void* d_out, int out_size, void* d_ws, size_t ws_size,
                              hipStream_t stream) {
    const float* x = (const float*)d_in[0];
    float* out = (float*)d_out;

    unsigned int* hist = (unsigned int*)d_ws;                     // 64*16*2560 u32 ~ 10.5 MB
    unsigned int* hist4 = hist + (size_t)BATCH * STRIPS * NFL;    // 64*640 u32
    float* smax = (float*)(hist4 + (size_t)BATCH * N4);           // 64*16 floats

    dim3 grid(STRIPS, BATCH);
    pass1_kernel<<<grid, NT, 0, stream>>>(x, hist, hist4, smax);
    finalize_kernel<<<BATCH, NT, 0, stream>>>(hist, hist4, smax, out);
}